// Round 1
// baseline (798.480 us; speedup 1.0000x reference)
//
#include <hip/hip_runtime.h>
#include <stdint.h>

// B=2,S=2048,D=1024,H=16,R=64,N=32,RK=128,DH=64. Tokens T=4096.
// Pipeline (all bf16 MFMA, fp32 accumulate, fp32 residuals):
//  transposes -> LN1 -> G_feat1 -> mix_attn -> G_qk/G_v -> flash -> G_O(+x)
//  -> LN2 -> G_feat2 -> mix_know -> G_know(+x1) -> d_out

typedef __bf16 bf16x8 __attribute__((ext_vector_type(8)));
typedef float f32x4 __attribute__((ext_vector_type(4)));

__device__ __forceinline__ unsigned short f2b(float f) {
  union { float f; unsigned u; } v; v.f = f;
  unsigned u = v.u;
  unsigned r = (u + 0x7FFFu + ((u >> 16) & 1u)) >> 16;  // RNE
  return (unsigned short)r;
}
__device__ __forceinline__ float b2f(unsigned short h) {
  union { unsigned u; float f; } v; v.u = ((unsigned)h) << 16;
  return v.f;
}

// ---------------------------------------------------------------------------
// Generic bf16 GEMM: C[M,N] = A[M,K] @ Bt[N,K]^T.  128x128 tile, BK=64,
// 256 threads (4 waves, 2x2 of 64x64), 16x16x32 MFMA, global_load_lds x16.
// mode 0: fp32 out; 1: bf16 out; 2: fp32 out + res; 3: bf16 transposed out[N,M]
// ---------------------------------------------------------------------------
__global__ __launch_bounds__(256) void gemm_bt(
    const unsigned short* __restrict__ A, const unsigned short* __restrict__ Bt,
    const float* __restrict__ res, void* __restrict__ out,
    int M, int N, int K, int mode) {
  __shared__ unsigned short lsA[128 * 64];
  __shared__ unsigned short lsB[128 * 64];
  const int tid = threadIdx.x;
  const int w = tid >> 6, lane = tid & 63;
  const int quad = lane >> 4, l16 = lane & 15;
  const int wr = w >> 1, wc = w & 1;
  const int row0 = blockIdx.y * 128;
  const int col0 = blockIdx.x * 128;

  // staging: each wave covers 32 rows of each tile; 4 instrs x (8 rows x 64 cols)
  const int srow = w * 32 + (lane >> 3);
  const int scg = (lane & 7) * 8;
  const unsigned short* ap = A + (size_t)(row0 + srow) * K + scg;
  const unsigned short* bp = Bt + (size_t)(col0 + srow) * K + scg;

  const f32x4 fz = {0.f, 0.f, 0.f, 0.f};
  f32x4 acc[4][4];
#pragma unroll
  for (int i = 0; i < 4; ++i)
#pragma unroll
    for (int j = 0; j < 4; ++j) acc[i][j] = fz;

  for (int k0 = 0; k0 < K; k0 += 64) {
#pragma unroll
    for (int i = 0; i < 4; ++i) {
      __builtin_amdgcn_global_load_lds(
          (const __attribute__((address_space(1))) unsigned int*)(ap + (size_t)i * 8 * K + k0),
          (__attribute__((address_space(3))) unsigned int*)&lsA[(w * 32 + i * 8) * 64],
          16, 0, 0);
      __builtin_amdgcn_global_load_lds(
          (const __attribute__((address_space(1))) unsigned int*)(bp + (size_t)i * 8 * K + k0),
          (__attribute__((address_space(3))) unsigned int*)&lsB[(w * 32 + i * 8) * 64],
          16, 0, 0);
    }
    __syncthreads();
#pragma unroll
    for (int kk = 0; kk < 2; ++kk) {
      bf16x8 af[4], bfr[4];
#pragma unroll
      for (int mt = 0; mt < 4; ++mt)
        af[mt] = *(const bf16x8*)&lsA[(wr * 64 + mt * 16 + l16) * 64 + kk * 32 + quad * 8];
#pragma unroll
      for (int nt = 0; nt < 4; ++nt)
        bfr[nt] = *(const bf16x8*)&lsB[(wc * 64 + nt * 16 + l16) * 64 + kk * 32 + quad * 8];
#pragma unroll
      for (int mt = 0; mt < 4; ++mt)
#pragma unroll
        for (int nt = 0; nt < 4; ++nt)
          acc[mt][nt] = __builtin_amdgcn_mfma_f32_16x16x32_bf16(af[mt], bfr[nt], acc[mt][nt], 0, 0, 0);
    }
    __syncthreads();
  }

  const int rb = row0 + wr * 64;
  const int cb = col0 + wc * 64;
#pragma unroll
  for (int mt = 0; mt < 4; ++mt) {
#pragma unroll
    for (int nt = 0; nt < 4; ++nt) {
      const int r = rb + mt * 16 + quad * 4;
      const int c = cb + nt * 16 + l16;
#pragma unroll
      for (int i = 0; i < 4; ++i) {
        const float v = acc[mt][nt][i];
        const size_t idx = (size_t)(r + i) * N + c;
        if (mode == 0) ((float*)out)[idx] = v;
        else if (mode == 1) ((unsigned short*)out)[idx] = f2b(v);
        else if (mode == 2) ((float*)out)[idx] = v + res[idx];
        else ((unsigned short*)out)[(size_t)c * M + (r + i)] = f2b(v);
      }
    }
  }
}

// ---------------------------------------------------------------------------
// LayerNorm over D=1024, one token per 256-thread block, bf16 out.
// ---------------------------------------------------------------------------
__global__ __launch_bounds__(256) void ln_kernel(
    const float* __restrict__ x, const float* __restrict__ g,
    const float* __restrict__ be, unsigned short* __restrict__ out) {
  __shared__ float sbuf[4];
  const int t = blockIdx.x, tid = threadIdx.x;
  const float* row = x + (size_t)t * 1024;
  float v[4], s = 0.f;
#pragma unroll
  for (int j = 0; j < 4; ++j) { v[j] = row[tid + j * 256]; s += v[j]; }
#pragma unroll
  for (int off = 32; off; off >>= 1) s += __shfl_xor(s, off);
  if ((tid & 63) == 0) sbuf[tid >> 6] = s;
  __syncthreads();
  const float mu = (sbuf[0] + sbuf[1] + sbuf[2] + sbuf[3]) * (1.f / 1024.f);
  __syncthreads();
  float ss = 0.f;
#pragma unroll
  for (int j = 0; j < 4; ++j) { const float d = v[j] - mu; ss += d * d; }
#pragma unroll
  for (int off = 32; off; off >>= 1) ss += __shfl_xor(ss, off);
  if ((tid & 63) == 0) sbuf[tid >> 6] = ss;
  __syncthreads();
  const float var = (sbuf[0] + sbuf[1] + sbuf[2] + sbuf[3]) * (1.f / 1024.f);
  const float rstd = rsqrtf(var + 1e-5f);
  unsigned short* orow = out + (size_t)t * 1024;
#pragma unroll
  for (int j = 0; j < 4; ++j) {
    const int c = tid + j * 256;
    orow[c] = f2b((v[j] - mu) * rstd * g[c] + be[c]);
  }
}

// ---------------------------------------------------------------------------
// Attention mixing: h_{q,k,v}[r] = sum_n w_f*[n]*all_h[t, (base)+n*64+r];
// t_*[t, n*64+r] = w_r*[n]*h_*[r].  all_h cols: [0,2048)=f_qk, [2048,4096)=f_v.
// ---------------------------------------------------------------------------
__global__ __launch_bounds__(256) void mix_attn(
    const unsigned short* __restrict__ all_h,
    const float* __restrict__ w_fq, const float* __restrict__ w_fk,
    const float* __restrict__ w_fv, const float* __restrict__ w_rq,
    const float* __restrict__ w_rk, const float* __restrict__ w_rv,
    unsigned short* __restrict__ t_qk, unsigned short* __restrict__ t_v) {
  __shared__ float hq[64], hk[64], hv[64];
  const int t = blockIdx.x, tid = threadIdx.x;
  const int wv = tid >> 6, lane = tid & 63;
  const unsigned short* row = all_h + (size_t)t * 4096;
  if (wv < 3) {
    const float* wf = (wv == 0 ? w_fq : wv == 1 ? w_fk : w_fv) + (size_t)t * 32;
    const int base = (wv == 2) ? 2048 : 0;
    float acc = 0.f;
#pragma unroll
    for (int n = 0; n < 32; ++n) acc += wf[n] * b2f(row[base + n * 64 + lane]);
    (wv == 0 ? hq : wv == 1 ? hk : hv)[lane] = acc;
  }
  __syncthreads();
  const float* wrq = w_rq + (size_t)t * 32;
  const float* wrk = w_rk + (size_t)t * 32;
  const float* wrv = w_rv + (size_t)t * 32;
  for (int idx = tid; idx < 2048; idx += 256) {
    const int n = idx >> 6, r = idx & 63;
    t_qk[(size_t)t * 2048 + idx] = f2b(wrq[n] * hq[r]);
    t_qk[(size_t)(4096 + t) * 2048 + idx] = f2b(wrk[n] * hk[r]);
    t_v[(size_t)t * 2048 + idx] = f2b(wrv[n] * hv[r]);
  }
}

// Knowledge mixing (RK=128): h[r]=sum_n w_f[n]*all_h[t,n*128+r]; t_know=w_r[n]*h[r]
__global__ __launch_bounds__(256) void mix_know(
    const unsigned short* __restrict__ all_h, const float* __restrict__ w_f,
    const float* __restrict__ w_r, unsigned short* __restrict__ t_know) {
  __shared__ float h[128];
  const int t = blockIdx.x, tid = threadIdx.x;
  const unsigned short* row = all_h + (size_t)t * 4096;
  if (tid < 128) {
    const float* wf = w_f + (size_t)t * 32;
    float acc = 0.f;
#pragma unroll
    for (int n = 0; n < 32; ++n) acc += wf[n] * b2f(row[n * 128 + tid]);
    h[tid] = acc;
  }
  __syncthreads();
  const float* wr = w_r + (size_t)t * 32;
  for (int idx = tid; idx < 4096; idx += 256) {
    const int n = idx >> 7, r = idx & 127;
    t_know[(size_t)t * 4096 + idx] = f2b(wr[n] * h[r]);
  }
}

// ---------------------------------------------------------------------------
// Batched transpose + fp32->bf16: in [batch][R][C] f32 -> out [batch][C][R] bf16
// ---------------------------------------------------------------------------
__global__ __launch_bounds__(256) void transpose_bf(
    const float* __restrict__ in, unsigned short* __restrict__ out, int R, int C) {
  __shared__ float tile[32][33];
  const int bb = blockIdx.z;
  const int c0 = blockIdx.x * 32, r0 = blockIdx.y * 32;
  const int tx = threadIdx.x, ty = threadIdx.y;
  const float* ip = in + (size_t)bb * R * C;
  unsigned short* op = out + (size_t)bb * R * C;
#pragma unroll
  for (int j = 0; j < 4; ++j)
    tile[ty + j * 8][tx] = ip[(size_t)(r0 + ty + j * 8) * C + c0 + tx];
  __syncthreads();
#pragma unroll
  for (int j = 0; j < 4; ++j)
    op[(size_t)(c0 + ty + j * 8) * R + r0 + tx] = f2b(tile[tx][ty + j * 8]);
}

__global__ __launch_bounds__(256) void convert_bf(
    const float* __restrict__ in, unsigned short* __restrict__ out, int n) {
  const int i = blockIdx.x * 256 + threadIdx.x;
  if (i < n) out[i] = f2b(in[i]);
}

// ---------------------------------------------------------------------------
// Causal flash attention. Q,K: bf16 [4096,1024] token-major; VT: bf16 [1024,4096]
// (d-major). Block = 64 q-rows (4 waves x 16), iterates K-tiles of 64.
// ---------------------------------------------------------------------------
__global__ __launch_bounds__(256) void flash_attn(
    const unsigned short* __restrict__ Q, const unsigned short* __restrict__ Kp,
    const unsigned short* __restrict__ VT, unsigned short* __restrict__ O) {
  __shared__ unsigned short Pl[4][16][64];
  const int qt = blockIdx.x, bh = blockIdx.y;
  const int b = bh >> 4, h = bh & 15;
  const int tid = threadIdx.x;
  const int w = tid >> 6, lane = tid & 63, quad = lane >> 4, l16 = lane & 15;
  const int tb = b * 2048;
  const int qrow = qt * 64 + w * 16;

  bf16x8 qf[2];
#pragma unroll
  for (int kk = 0; kk < 2; ++kk)
    qf[kk] = *(const bf16x8*)&Q[(size_t)(tb + qrow + l16) * 1024 + h * 64 + kk * 32 + quad * 8];

  const f32x4 fz = {0.f, 0.f, 0.f, 0.f};
  float m_i[4] = {-1e30f, -1e30f, -1e30f, -1e30f};
  float l_i[4] = {0.f, 0.f, 0.f, 0.f};
  f32x4 o_acc[4];
#pragma unroll
  for (int nt = 0; nt < 4; ++nt) o_acc[nt] = fz;

  for (int kt = 0; kt <= qt; ++kt) {
    f32x4 s[4];
#pragma unroll
    for (int nt = 0; nt < 4; ++nt) s[nt] = fz;
#pragma unroll
    for (int kk = 0; kk < 2; ++kk)
#pragma unroll
      for (int nt = 0; nt < 4; ++nt) {
        bf16x8 kf = *(const bf16x8*)&Kp[(size_t)(tb + kt * 64 + nt * 16 + l16) * 1024 + h * 64 + kk * 32 + quad * 8];
        s[nt] = __builtin_amdgcn_mfma_f32_16x16x32_bf16(qf[kk], kf, s[nt], 0, 0, 0);
      }
    const bool diag = (kt == qt);
    float mx[4] = {-1e30f, -1e30f, -1e30f, -1e30f};
#pragma unroll
    for (int nt = 0; nt < 4; ++nt)
#pragma unroll
      for (int i = 0; i < 4; ++i) {
        float v = s[nt][i] * 0.125f;  // 1/sqrt(64)
        if (diag && (nt * 16 + l16) > (w * 16 + quad * 4 + i)) v = -1e30f;
        s[nt][i] = v;
        mx[i] = fmaxf(mx[i], v);
      }
#pragma unroll
    for (int off = 1; off < 16; off <<= 1)
#pragma unroll
      for (int i = 0; i < 4; ++i) mx[i] = fmaxf(mx[i], __shfl_xor(mx[i], off));
    float al[4], rs[4];
#pragma unroll
    for (int i = 0; i < 4; ++i) {
      const float mn = fmaxf(m_i[i], mx[i]);
      al[i] = __expf(m_i[i] - mn);
      m_i[i] = mn;
      rs[i] = 0.f;
    }
#pragma unroll
    for (int nt = 0; nt < 4; ++nt)
#pragma unroll
      for (int i = 0; i < 4; ++i) {
        const float p = __expf(s[nt][i] - m_i[i]);
        s[nt][i] = p;
        rs[i] += p;
      }
#pragma unroll
    for (int off = 1; off < 16; off <<= 1)
#pragma unroll
      for (int i = 0; i < 4; ++i) rs[i] += __shfl_xor(rs[i], off);
#pragma unroll
    for (int i = 0; i < 4; ++i) l_i[i] = l_i[i] * al[i] + rs[i];
#pragma unroll
    for (int nt = 0; nt < 4; ++nt)
#pragma unroll
      for (int i = 0; i < 4; ++i) o_acc[nt][i] *= al[i];
    // P (C-layout) -> A-frag via per-wave LDS round-trip
#pragma unroll
    for (int nt = 0; nt < 4; ++nt)
#pragma unroll
      for (int i = 0; i < 4; ++i) Pl[w][quad * 4 + i][nt * 16 + l16] = f2b(s[nt][i]);
    bf16x8 pf[2];
#pragma unroll
    for (int kk = 0; kk < 2; ++kk)
      pf[kk] = *(const bf16x8*)&Pl[w][l16][kk * 32 + quad * 8];
#pragma unroll
    for (int kk = 0; kk < 2; ++kk)
#pragma unroll
      for (int nt = 0; nt < 4; ++nt) {
        bf16x8 vf = *(const bf16x8*)&VT[(size_t)(h * 64 + nt * 16 + l16) * 4096 + tb + kt * 64 + kk * 32 + quad * 8];
        o_acc[nt] = __builtin_amdgcn_mfma_f32_16x16x32_bf16(pf[kk], vf, o_acc[nt], 0, 0, 0);
      }
  }
#pragma unroll
  for (int nt = 0; nt < 4; ++nt)
#pragma unroll
    for (int i = 0; i < 4; ++i)
      O[(size_t)(tb + qrow + quad * 4 + i) * 1024 + h * 64 + nt * 16 + l16] =
          f2b(o_acc[nt][i] / l_i[i]);
}

// ---------------------------------------------------------------------------
extern "C" void kernel_launch(void* const* d_in, const int* in_sizes, int n_in,
                              void* d_out, int out_size, void* d_ws, size_t ws_size,
                              hipStream_t stream) {
  (void)in_sizes; (void)n_in; (void)out_size; (void)ws_size;
  const float* x      = (const float*)d_in[0];
  const float* f_qk   = (const float*)d_in[1];
  const float* f_v    = (const float*)d_in[2];
  const float* r_qk   = (const float*)d_in[3];
  const float* r_v    = (const float*)d_in[4];
  const float* f_know = (const float*)d_in[5];
  const float* r_know = (const float*)d_in[6];
  const float* W_O    = (const float*)d_in[7];
  const float* gamma1 = (const float*)d_in[8];
  const float* beta1  = (const float*)d_in[9];
  const float* gamma2 = (const float*)d_in[10];
  const float* beta2  = (const float*)d_in[11];
  const float* w_fq   = (const float*)d_in[12];
  const float* w_fk   = (const float*)d_in[13];
  const float* w_fv   = (const float*)d_in[14];
  const float* w_rq   = (const float*)d_in[15];
  const float* w_rk   = (const float*)d_in[16];
  const float* w_rv   = (const float*)d_in[17];
  const float* w_kf   = (const float*)d_in[18];
  const float* w_kr   = (const float*)d_in[19];

  char* base = (char*)d_ws;
  size_t off = 0;
  auto alloc = [&](size_t b) { char* p = base + off; off += (b + 255) & ~(size_t)255; return p; };
  // persistent bf16 weight layouts ([N][K] for gemm_bt)
  unsigned short* fcomb   = (unsigned short*)alloc(8388608);   // [4096][1024]: rows 0..2047 f_qk, 2048.. f_v
  unsigned short* fknowT  = (unsigned short*)alloc(8388608);   // [4096][1024]
  unsigned short* r_qkT   = (unsigned short*)alloc(4194304);   // [1024][2048]
  unsigned short* r_vT    = (unsigned short*)alloc(4194304);   // [1024][2048]
  unsigned short* r_knowT = (unsigned short*)alloc(8388608);   // [1024][4096]
  unsigned short* WO_bf   = (unsigned short*)alloc(2097152);   // [1024][1024] (natural = [N][K])
  // activations
  unsigned short* nx_bf   = (unsigned short*)alloc(8388608);   // [4096][1024] (reused for LN2)
  unsigned short* all_h   = (unsigned short*)alloc(33554432);  // [4096][4096] bf16 (reused, knowledge)
  unsigned short* t_qk    = (unsigned short*)alloc(33554432);  // [8192][2048] (reused as t_know [4096][4096])
  unsigned short* t_v     = (unsigned short*)alloc(16777216);  // [4096][2048]; later reused as x1 fp32
  unsigned short* QKbuf   = (unsigned short*)alloc(16777216);  // [8192][1024] bf16: Q rows 0..4095, K rows 4096..
  unsigned short* VT      = (unsigned short*)alloc(8388608);   // [1024][4096] bf16
  unsigned short* attn    = (unsigned short*)alloc(8388608);   // [4096][1024] bf16
  float* x1 = (float*)t_v;  // t_v dead before x1 written

  const dim3 blk256(256), blkT(32, 8);

  // weight preps
  transpose_bf<<<dim3(2, 32, 32), blkT, 0, stream>>>(f_qk, fcomb, 1024, 64);
  transpose_bf<<<dim3(2, 32, 32), blkT, 0, stream>>>(f_v, fcomb + (size_t)2048 * 1024, 1024, 64);
  transpose_bf<<<dim3(4, 32, 32), blkT, 0, stream>>>(f_know, fknowT, 1024, 128);
  transpose_bf<<<dim3(32, 64, 1), blkT, 0, stream>>>(r_qk, r_qkT, 2048, 1024);
  transpose_bf<<<dim3(32, 64, 1), blkT, 0, stream>>>(r_v, r_vT, 2048, 1024);
  transpose_bf<<<dim3(32, 128, 1), blkT, 0, stream>>>(r_know, r_knowT, 4096, 1024);
  convert_bf<<<4096, blk256, 0, stream>>>(W_O, WO_bf, 1048576);

  // attention circuit
  ln_kernel<<<4096, blk256, 0, stream>>>(x, gamma1, beta1, nx_bf);
  gemm_bt<<<dim3(32, 32), blk256, 0, stream>>>(nx_bf, fcomb, nullptr, all_h, 4096, 4096, 1024, 1);
  mix_attn<<<4096, blk256, 0, stream>>>(all_h, w_fq, w_fk, w_fv, w_rq, w_rk, w_rv, t_qk, t_v);
  gemm_bt<<<dim3(8, 64), blk256, 0, stream>>>(t_qk, r_qkT, nullptr, QKbuf, 8192, 1024, 2048, 1);
  gemm_bt<<<dim3(8, 32), blk256, 0, stream>>>(t_v, r_vT, nullptr, VT, 4096, 1024, 2048, 3);
  flash_attn<<<dim3(32, 32), blk256, 0, stream>>>(QKbuf, QKbuf + (size_t)4096 * 1024, VT, attn);
  gemm_bt<<<dim3(8, 32), blk256, 0, stream>>>(attn, WO_bf, x, x1, 4096, 1024, 1024, 2);

  // knowledge circuit
  ln_kernel<<<4096, blk256, 0, stream>>>(x1, gamma2, beta2, nx_bf);
  gemm_bt<<<dim3(32, 32), blk256, 0, stream>>>(nx_bf, fknowT, nullptr, all_h, 4096, 4096, 1024, 1);
  mix_know<<<4096, blk256, 0, stream>>>(all_h, w_kf, w_kr, t_qk);
  gemm_bt<<<dim3(8, 32), blk256, 0, stream>>>(t_qk, r_knowT, x1, (float*)d_out, 4096, 1024, 4096, 2);
}

// Round 2
// 719.594 us; speedup vs baseline: 1.1096x; 1.1096x over previous
//
#include <hip/hip_runtime.h>
#include <stdint.h>

// B=2,S=2048,D=1024,H=16,R=64,N=32,RK=128,DH=64. Tokens T=4096.
// Pipeline (all bf16 MFMA, fp32 accumulate, fp32 residuals):
//  transposes -> LN1 -> G_feat1 -> mix_attn -> G_qk/G_v -> flash -> G_O(+x)
//  -> LN2 -> G_feat2 -> mix_know -> G_know(+x1) -> d_out

typedef __bf16 bf16x8 __attribute__((ext_vector_type(8)));
typedef float f32x4 __attribute__((ext_vector_type(4)));

__device__ __forceinline__ unsigned short f2b(float f) {
  union { float f; unsigned u; } v; v.f = f;
  unsigned u = v.u;
  unsigned r = (u + 0x7FFFu + ((u >> 16) & 1u)) >> 16;  // RNE
  return (unsigned short)r;
}
__device__ __forceinline__ float b2f(unsigned short h) {
  union { unsigned u; float f; } v; v.u = ((unsigned)h) << 16;
  return v.f;
}

// ---------------------------------------------------------------------------
// Generic bf16 GEMM: C[M,N] = A[M,K] @ Bt[N,K]^T.  128x128 tile, BK=64,
// 256 threads (4 waves, 2x2 of 64x64), 16x16x32 MFMA, global_load_lds x16.
// mode 0: fp32 out; 1: bf16 out; 2: fp32 out + res; 3: bf16 transposed out[N,M]
// ---------------------------------------------------------------------------
__global__ __launch_bounds__(256) void gemm_bt(
    const unsigned short* __restrict__ A, const unsigned short* __restrict__ Bt,
    const float* __restrict__ res, void* __restrict__ out,
    int M, int N, int K, int mode) {
  __shared__ unsigned short lsA[128 * 64];
  __shared__ unsigned short lsB[128 * 64];
  const int tid = threadIdx.x;
  const int w = tid >> 6, lane = tid & 63;
  const int quad = lane >> 4, l16 = lane & 15;
  const int wr = w >> 1, wc = w & 1;
  const int row0 = blockIdx.y * 128;
  const int col0 = blockIdx.x * 128;

  // staging: each wave covers 32 rows of each tile; 4 instrs x (8 rows x 64 cols)
  const int srow = w * 32 + (lane >> 3);
  const int scg = (lane & 7) * 8;
  const unsigned short* ap = A + (size_t)(row0 + srow) * K + scg;
  const unsigned short* bp = Bt + (size_t)(col0 + srow) * K + scg;

  const f32x4 fz = {0.f, 0.f, 0.f, 0.f};
  f32x4 acc[4][4];
#pragma unroll
  for (int i = 0; i < 4; ++i)
#pragma unroll
    for (int j = 0; j < 4; ++j) acc[i][j] = fz;

  for (int k0 = 0; k0 < K; k0 += 64) {
#pragma unroll
    for (int i = 0; i < 4; ++i) {
      __builtin_amdgcn_global_load_lds(
          (const __attribute__((address_space(1))) unsigned int*)(ap + (size_t)i * 8 * K + k0),
          (__attribute__((address_space(3))) unsigned int*)&lsA[(w * 32 + i * 8) * 64],
          16, 0, 0);
      __builtin_amdgcn_global_load_lds(
          (const __attribute__((address_space(1))) unsigned int*)(bp + (size_t)i * 8 * K + k0),
          (__attribute__((address_space(3))) unsigned int*)&lsB[(w * 32 + i * 8) * 64],
          16, 0, 0);
    }
    __syncthreads();
#pragma unroll
    for (int kk = 0; kk < 2; ++kk) {
      bf16x8 af[4], bfr[4];
#pragma unroll
      for (int mt = 0; mt < 4; ++mt)
        af[mt] = *(const bf16x8*)&lsA[(wr * 64 + mt * 16 + l16) * 64 + kk * 32 + quad * 8];
#pragma unroll
      for (int nt = 0; nt < 4; ++nt)
        bfr[nt] = *(const bf16x8*)&lsB[(wc * 64 + nt * 16 + l16) * 64 + kk * 32 + quad * 8];
#pragma unroll
      for (int mt = 0; mt < 4; ++mt)
#pragma unroll
        for (int nt = 0; nt < 4; ++nt)
          acc[mt][nt] = __builtin_amdgcn_mfma_f32_16x16x32_bf16(af[mt], bfr[nt], acc[mt][nt], 0, 0, 0);
    }
    __syncthreads();
  }

  const int rb = row0 + wr * 64;
  const int cb = col0 + wc * 64;
#pragma unroll
  for (int mt = 0; mt < 4; ++mt) {
#pragma unroll
    for (int nt = 0; nt < 4; ++nt) {
      const int r = rb + mt * 16 + quad * 4;
      const int c = cb + nt * 16 + l16;
#pragma unroll
      for (int i = 0; i < 4; ++i) {
        const float v = acc[mt][nt][i];
        const size_t idx = (size_t)(r + i) * N + c;
        if (mode == 0) ((float*)out)[idx] = v;
        else if (mode == 1) ((unsigned short*)out)[idx] = f2b(v);
        else if (mode == 2) ((float*)out)[idx] = v + res[idx];
        else ((unsigned short*)out)[(size_t)c * M + (r + i)] = f2b(v);
      }
    }
  }
}

// ---------------------------------------------------------------------------
// LayerNorm over D=1024, one token per 256-thread block, bf16 out.
// ---------------------------------------------------------------------------
__global__ __launch_bounds__(256) void ln_kernel(
    const float* __restrict__ x, const float* __restrict__ g,
    const float* __restrict__ be, unsigned short* __restrict__ out) {
  __shared__ float sbuf[4];
  const int t = blockIdx.x, tid = threadIdx.x;
  const float* row = x + (size_t)t * 1024;
  float v[4], s = 0.f;
#pragma unroll
  for (int j = 0; j < 4; ++j) { v[j] = row[tid + j * 256]; s += v[j]; }
#pragma unroll
  for (int off = 32; off; off >>= 1) s += __shfl_xor(s, off);
  if ((tid & 63) == 0) sbuf[tid >> 6] = s;
  __syncthreads();
  const float mu = (sbuf[0] + sbuf[1] + sbuf[2] + sbuf[3]) * (1.f / 1024.f);
  __syncthreads();
  float ss = 0.f;
#pragma unroll
  for (int j = 0; j < 4; ++j) { const float d = v[j] - mu; ss += d * d; }
#pragma unroll
  for (int off = 32; off; off >>= 1) ss += __shfl_xor(ss, off);
  if ((tid & 63) == 0) sbuf[tid >> 6] = ss;
  __syncthreads();
  const float var = (sbuf[0] + sbuf[1] + sbuf[2] + sbuf[3]) * (1.f / 1024.f);
  const float rstd = rsqrtf(var + 1e-5f);
  unsigned short* orow = out + (size_t)t * 1024;
#pragma unroll
  for (int j = 0; j < 4; ++j) {
    const int c = tid + j * 256;
    orow[c] = f2b((v[j] - mu) * rstd * g[c] + be[c]);
  }
}

// ---------------------------------------------------------------------------
// Attention mixing: h_{q,k,v}[r] = sum_n w_f*[n]*all_h[t, (base)+n*64+r];
// t_*[t, n*64+r] = w_r*[n]*h_*[r].  all_h cols: [0,2048)=f_qk, [2048,4096)=f_v.
// ---------------------------------------------------------------------------
__global__ __launch_bounds__(256) void mix_attn(
    const unsigned short* __restrict__ all_h,
    const float* __restrict__ w_fq, const float* __restrict__ w_fk,
    const float* __restrict__ w_fv, const float* __restrict__ w_rq,
    const float* __restrict__ w_rk, const float* __restrict__ w_rv,
    unsigned short* __restrict__ t_qk, unsigned short* __restrict__ t_v) {
  __shared__ float hq[64], hk[64], hv[64];
  const int t = blockIdx.x, tid = threadIdx.x;
  const int wv = tid >> 6, lane = tid & 63;
  const unsigned short* row = all_h + (size_t)t * 4096;
  if (wv < 3) {
    const float* wf = (wv == 0 ? w_fq : wv == 1 ? w_fk : w_fv) + (size_t)t * 32;
    const int base = (wv == 2) ? 2048 : 0;
    float acc = 0.f;
#pragma unroll
    for (int n = 0; n < 32; ++n) acc += wf[n] * b2f(row[base + n * 64 + lane]);
    (wv == 0 ? hq : wv == 1 ? hk : hv)[lane] = acc;
  }
  __syncthreads();
  const float* wrq = w_rq + (size_t)t * 32;
  const float* wrk = w_rk + (size_t)t * 32;
  const float* wrv = w_rv + (size_t)t * 32;
  for (int idx = tid; idx < 2048; idx += 256) {
    const int n = idx >> 6, r = idx & 63;
    t_qk[(size_t)t * 2048 + idx] = f2b(wrq[n] * hq[r]);
    t_qk[(size_t)(4096 + t) * 2048 + idx] = f2b(wrk[n] * hk[r]);
    t_v[(size_t)t * 2048 + idx] = f2b(wrv[n] * hv[r]);
  }
}

// Knowledge mixing (RK=128): h[r]=sum_n w_f[n]*all_h[t,n*128+r]; t_know=w_r[n]*h[r]
__global__ __launch_bounds__(256) void mix_know(
    const unsigned short* __restrict__ all_h, const float* __restrict__ w_f,
    const float* __restrict__ w_r, unsigned short* __restrict__ t_know) {
  __shared__ float h[128];
  const int t = blockIdx.x, tid = threadIdx.x;
  const unsigned short* row = all_h + (size_t)t * 4096;
  if (tid < 128) {
    const float* wf = w_f + (size_t)t * 32;
    float acc = 0.f;
#pragma unroll
    for (int n = 0; n < 32; ++n) acc += wf[n] * b2f(row[n * 128 + tid]);
    h[tid] = acc;
  }
  __syncthreads();
  const float* wr = w_r + (size_t)t * 32;
  for (int idx = tid; idx < 4096; idx += 256) {
    const int n = idx >> 7, r = idx & 127;
    t_know[(size_t)t * 4096 + idx] = f2b(wr[n] * h[r]);
  }
}

// ---------------------------------------------------------------------------
// Batched transpose + fp32->bf16: in [batch][R][C] f32 -> out [batch][C][R] bf16
// ---------------------------------------------------------------------------
__global__ __launch_bounds__(256) void transpose_bf(
    const float* __restrict__ in, unsigned short* __restrict__ out, int R, int C) {
  __shared__ float tile[32][33];
  const int bb = blockIdx.z;
  const int c0 = blockIdx.x * 32, r0 = blockIdx.y * 32;
  const int tx = threadIdx.x, ty = threadIdx.y;
  const float* ip = in + (size_t)bb * R * C;
  unsigned short* op = out + (size_t)bb * R * C;
#pragma unroll
  for (int j = 0; j < 4; ++j)
    tile[ty + j * 8][tx] = ip[(size_t)(r0 + ty + j * 8) * C + c0 + tx];
  __syncthreads();
#pragma unroll
  for (int j = 0; j < 4; ++j)
    op[(size_t)(c0 + ty + j * 8) * R + r0 + tx] = f2b(tile[tx][ty + j * 8]);
}

__global__ __launch_bounds__(256) void convert_bf(
    const float* __restrict__ in, unsigned short* __restrict__ out, int n) {
  const int i = blockIdx.x * 256 + threadIdx.x;
  if (i < n) out[i] = f2b(in[i]);
}

// ---------------------------------------------------------------------------
// Causal flash attention v2: LDS-staged, double-buffered K/V tiles.
// Q,K: bf16 [4096,1024] token-major; VT: bf16 [1024,4096] d-major.
// Block = 64 q-rows (4 waves x 16 rows), iterates 64-token K-tiles.
// K tile [64 tok][64 d], V tile [64 d][64 tok] staged via global_load_lds x16.
// ---------------------------------------------------------------------------
__global__ __launch_bounds__(256) void flash_attn(
    const unsigned short* __restrict__ Q, const unsigned short* __restrict__ Kp,
    const unsigned short* __restrict__ VT, unsigned short* __restrict__ O) {
  __shared__ unsigned short Kls[2][64 * 64];
  __shared__ unsigned short Vls[2][64 * 64];
  __shared__ unsigned short Pl[4][16][64];
  const int qt = blockIdx.x, bh = blockIdx.y;
  const int b = bh >> 4, h = bh & 15;
  const int tid = threadIdx.x;
  const int w = tid >> 6, lane = tid & 63, quad = lane >> 4, l16 = lane & 15;
  const int tb = b * 2048;
  const int qrow = qt * 64 + w * 16;

  // staging source offsets for this lane (8 lanes per 64-elem row)
  const int srow = (lane >> 3);      // 0..7 within the 8-row group
  const int scol = (lane & 7) * 8;   // elem offset within row

  bf16x8 qf[2];
#pragma unroll
  for (int kk = 0; kk < 2; ++kk)
    qf[kk] = *(const bf16x8*)&Q[(size_t)(tb + qrow + l16) * 1024 + h * 64 + kk * 32 + quad * 8];

  const f32x4 fz = {0.f, 0.f, 0.f, 0.f};
  float m_i[4] = {-1e30f, -1e30f, -1e30f, -1e30f};
  float l_i[4] = {0.f, 0.f, 0.f, 0.f};
  f32x4 o_acc[4];
#pragma unroll
  for (int nt = 0; nt < 4; ++nt) o_acc[nt] = fz;

  // stage K/V tile kt into buffer buf (all 4 waves, 2 instrs each per array)
  auto stage = [&](int buf, int kt) {
#pragma unroll
    for (int j = 0; j < 2; ++j) {
      const int rg = (w * 2 + j) * 8 + srow;  // 0..63
      __builtin_amdgcn_global_load_lds(
          (const __attribute__((address_space(1))) unsigned int*)
              (Kp + (size_t)(tb + kt * 64 + rg) * 1024 + h * 64 + scol),
          (__attribute__((address_space(3))) unsigned int*)&Kls[buf][(w * 2 + j) * 8 * 64],
          16, 0, 0);
      __builtin_amdgcn_global_load_lds(
          (const __attribute__((address_space(1))) unsigned int*)
              (VT + (size_t)(h * 64 + rg) * 4096 + tb + kt * 64 + scol),
          (__attribute__((address_space(3))) unsigned int*)&Vls[buf][(w * 2 + j) * 8 * 64],
          16, 0, 0);
    }
  };

  stage(0, 0);
  __syncthreads();
  int buf = 0;
  for (int kt = 0; kt <= qt; ++kt) {
    if (kt < qt) stage(buf ^ 1, kt + 1);  // in flight during compute
    f32x4 s[4];
#pragma unroll
    for (int nt = 0; nt < 4; ++nt) s[nt] = fz;
#pragma unroll
    for (int kk = 0; kk < 2; ++kk)
#pragma unroll
      for (int nt = 0; nt < 4; ++nt) {
        bf16x8 kf = *(const bf16x8*)&Kls[buf][(nt * 16 + l16) * 64 + kk * 32 + quad * 8];
        s[nt] = __builtin_amdgcn_mfma_f32_16x16x32_bf16(qf[kk], kf, s[nt], 0, 0, 0);
      }
    const bool diag = (kt == qt);
    float mx[4] = {-1e30f, -1e30f, -1e30f, -1e30f};
#pragma unroll
    for (int nt = 0; nt < 4; ++nt)
#pragma unroll
      for (int i = 0; i < 4; ++i) {
        float v = s[nt][i] * 0.125f;  // 1/sqrt(64)
        if (diag && (nt * 16 + l16) > (w * 16 + quad * 4 + i)) v = -1e30f;
        s[nt][i] = v;
        mx[i] = fmaxf(mx[i], v);
      }
#pragma unroll
    for (int off = 1; off < 16; off <<= 1)
#pragma unroll
      for (int i = 0; i < 4; ++i) mx[i] = fmaxf(mx[i], __shfl_xor(mx[i], off));
    float al[4], rs[4];
#pragma unroll
    for (int i = 0; i < 4; ++i) {
      const float mn = fmaxf(m_i[i], mx[i]);
      al[i] = __expf(m_i[i] - mn);
      m_i[i] = mn;
      rs[i] = 0.f;
    }
#pragma unroll
    for (int nt = 0; nt < 4; ++nt)
#pragma unroll
      for (int i = 0; i < 4; ++i) {
        const float p = __expf(s[nt][i] - m_i[i]);
        s[nt][i] = p;
        rs[i] += p;
      }
#pragma unroll
    for (int off = 1; off < 16; off <<= 1)
#pragma unroll
      for (int i = 0; i < 4; ++i) rs[i] += __shfl_xor(rs[i], off);
#pragma unroll
    for (int i = 0; i < 4; ++i) l_i[i] = l_i[i] * al[i] + rs[i];
#pragma unroll
    for (int nt = 0; nt < 4; ++nt)
#pragma unroll
      for (int i = 0; i < 4; ++i) o_acc[nt][i] *= al[i];
    // P (C-layout) -> A-frag via per-wave LDS round-trip
#pragma unroll
    for (int nt = 0; nt < 4; ++nt)
#pragma unroll
      for (int i = 0; i < 4; ++i) Pl[w][quad * 4 + i][nt * 16 + l16] = f2b(s[nt][i]);
    bf16x8 pf[2];
#pragma unroll
    for (int kk = 0; kk < 2; ++kk)
      pf[kk] = *(const bf16x8*)&Pl[w][l16][kk * 32 + quad * 8];
#pragma unroll
    for (int kk = 0; kk < 2; ++kk)
#pragma unroll
      for (int nt = 0; nt < 4; ++nt) {
        bf16x8 vf = *(const bf16x8*)&Vls[buf][(nt * 16 + l16) * 64 + kk * 32 + quad * 8];
        o_acc[nt] = __builtin_amdgcn_mfma_f32_16x16x32_bf16(pf[kk], vf, o_acc[nt], 0, 0, 0);
      }
    __syncthreads();  // drains prefetch vmcnt + guards LDS buffer reuse
    buf ^= 1;
  }
#pragma unroll
  for (int nt = 0; nt < 4; ++nt)
#pragma unroll
    for (int i = 0; i < 4; ++i)
      O[(size_t)(tb + qrow + quad * 4 + i) * 1024 + h * 64 + nt * 16 + l16] =
          f2b(o_acc[nt][i] / l_i[i]);
}

// ---------------------------------------------------------------------------
extern "C" void kernel_launch(void* const* d_in, const int* in_sizes, int n_in,
                              void* d_out, int out_size, void* d_ws, size_t ws_size,
                              hipStream_t stream) {
  (void)in_sizes; (void)n_in; (void)out_size; (void)ws_size;
  const float* x      = (const float*)d_in[0];
  const float* f_qk   = (const float*)d_in[1];
  const float* f_v    = (const float*)d_in[2];
  const float* r_qk   = (const float*)d_in[3];
  const float* r_v    = (const float*)d_in[4];
  const float* f_know = (const float*)d_in[5];
  const float* r_know = (const float*)d_in[6];
  const float* W_O    = (const float*)d_in[7];
  const float* gamma1 = (const float*)d_in[8];
  const float* beta1  = (const float*)d_in[9];
  const float* gamma2 = (const float*)d_in[10];
  const float* beta2  = (const float*)d_in[11];
  const float* w_fq   = (const float*)d_in[12];
  const float* w_fk   = (const float*)d_in[13];
  const float* w_fv   = (const float*)d_in[14];
  const float* w_rq   = (const float*)d_in[15];
  const float* w_rk   = (const float*)d_in[16];
  const float* w_rv   = (const float*)d_in[17];
  const float* w_kf   = (const float*)d_in[18];
  const float* w_kr   = (const float*)d_in[19];

  char* base = (char*)d_ws;
  size_t off = 0;
  auto alloc = [&](size_t b) { char* p = base + off; off += (b + 255) & ~(size_t)255; return p; };
  // persistent bf16 weight layouts ([N][K] for gemm_bt)
  unsigned short* fcomb   = (unsigned short*)alloc(8388608);   // [4096][1024]: rows 0..2047 f_qk, 2048.. f_v
  unsigned short* fknowT  = (unsigned short*)alloc(8388608);   // [4096][1024]
  unsigned short* r_qkT   = (unsigned short*)alloc(4194304);   // [1024][2048]
  unsigned short* r_vT    = (unsigned short*)alloc(4194304);   // [1024][2048]
  unsigned short* r_knowT = (unsigned short*)alloc(8388608);   // [1024][4096]
  unsigned short* WO_bf   = (unsigned short*)alloc(2097152);   // [1024][1024] (natural = [N][K])
  // activations
  unsigned short* nx_bf   = (unsigned short*)alloc(8388608);   // [4096][1024] (reused for LN2)
  unsigned short* all_h   = (unsigned short*)alloc(33554432);  // [4096][4096] bf16 (reused, knowledge)
  unsigned short* t_qk    = (unsigned short*)alloc(33554432);  // [8192][2048] (reused as t_know [4096][4096])
  unsigned short* t_v     = (unsigned short*)alloc(16777216);  // [4096][2048]; later reused as x1 fp32
  unsigned short* QKbuf   = (unsigned short*)alloc(16777216);  // [8192][1024] bf16: Q rows 0..4095, K rows 4096..
  unsigned short* VT      = (unsigned short*)alloc(8388608);   // [1024][4096] bf16
  unsigned short* attn    = (unsigned short*)alloc(8388608);   // [4096][1024] bf16
  float* x1 = (float*)t_v;  // t_v dead before x1 written

  const dim3 blk256(256), blkT(32, 8);

  // weight preps
  transpose_bf<<<dim3(2, 32, 32), blkT, 0, stream>>>(f_qk, fcomb, 1024, 64);
  transpose_bf<<<dim3(2, 32, 32), blkT, 0, stream>>>(f_v, fcomb + (size_t)2048 * 1024, 1024, 64);
  transpose_bf<<<dim3(4, 32, 32), blkT, 0, stream>>>(f_know, fknowT, 1024, 128);
  transpose_bf<<<dim3(32, 64, 1), blkT, 0, stream>>>(r_qk, r_qkT, 2048, 1024);
  transpose_bf<<<dim3(32, 64, 1), blkT, 0, stream>>>(r_v, r_vT, 2048, 1024);
  transpose_bf<<<dim3(32, 128, 1), blkT, 0, stream>>>(r_know, r_knowT, 4096, 1024);
  convert_bf<<<4096, blk256, 0, stream>>>(W_O, WO_bf, 1048576);

  // attention circuit
  ln_kernel<<<4096, blk256, 0, stream>>>(x, gamma1, beta1, nx_bf);
  gemm_bt<<<dim3(32, 32), blk256, 0, stream>>>(nx_bf, fcomb, nullptr, all_h, 4096, 4096, 1024, 1);
  mix_attn<<<4096, blk256, 0, stream>>>(all_h, w_fq, w_fk, w_fv, w_rq, w_rk, w_rv, t_qk, t_v);
  gemm_bt<<<dim3(8, 64), blk256, 0, stream>>>(t_qk, r_qkT, nullptr, QKbuf, 8192, 1024, 2048, 1);
  gemm_bt<<<dim3(8, 32), blk256, 0, stream>>>(t_v, r_vT, nullptr, VT, 4096, 1024, 2048, 3);
  flash_attn<<<dim3(32, 32), blk256, 0, stream>>>(QKbuf, QKbuf + (size_t)4096 * 1024, VT, attn);
  gemm_bt<<<dim3(8, 32), blk256, 0, stream>>>(attn, WO_bf, x, x1, 4096, 1024, 1024, 2);

  // knowledge circuit
  ln_kernel<<<4096, blk256, 0, stream>>>(x1, gamma2, beta2, nx_bf);
  gemm_bt<<<dim3(32, 32), blk256, 0, stream>>>(nx_bf, fknowT, nullptr, all_h, 4096, 4096, 1024, 1);
  mix_know<<<4096, blk256, 0, stream>>>(all_h, w_kf, w_kr, t_qk);
  gemm_bt<<<dim3(8, 32), blk256, 0, stream>>>(t_qk, r_knowT, x1, (float*)d_out, 4096, 1024, 4096, 2);
}

// Round 3
// 705.908 us; speedup vs baseline: 1.1311x; 1.0194x over previous
//
#include <hip/hip_runtime.h>
#include <stdint.h>

// B=2,S=2048,D=1024,H=16,R=64,N=32,RK=128,DH=64. Tokens T=4096.
// Pipeline (all bf16 MFMA, fp32 accumulate, fp32 residuals):
//  transposes -> LN1 -> G_feat1 -> mix_attn -> G_qk/G_v -> flash -> G_O(+x)
//  -> LN2 -> G_feat2 -> mix_know -> G_know(+x1) -> d_out

typedef __bf16 bf16x8 __attribute__((ext_vector_type(8)));
typedef float f32x4 __attribute__((ext_vector_type(4)));

__device__ __forceinline__ unsigned short f2b(float f) {
  union { float f; unsigned u; } v; v.f = f;
  unsigned u = v.u;
  unsigned r = (u + 0x7FFFu + ((u >> 16) & 1u)) >> 16;  // RNE
  return (unsigned short)r;
}
__device__ __forceinline__ float b2f(unsigned short h) {
  union { unsigned u; float f; } v; v.u = ((unsigned)h) << 16;
  return v.f;
}

// ---------------------------------------------------------------------------
// Generic bf16 GEMM: C[M,N] = A[M,K] @ Bt[N,K]^T.  128x128 tile, BK=64,
// 256 threads (4 waves, 2x2 of 64x64), 16x16x32 MFMA, global_load_lds x16.
// mode 0: fp32 out; 1: bf16 out; 2: fp32 out + res; 3: bf16 transposed out[N,M]
// ---------------------------------------------------------------------------
__global__ __launch_bounds__(256) void gemm_bt(
    const unsigned short* __restrict__ A, const unsigned short* __restrict__ Bt,
    const float* __restrict__ res, void* __restrict__ out,
    int M, int N, int K, int mode) {
  __shared__ unsigned short lsA[128 * 64];
  __shared__ unsigned short lsB[128 * 64];
  const int tid = threadIdx.x;
  const int w = tid >> 6, lane = tid & 63;
  const int quad = lane >> 4, l16 = lane & 15;
  const int wr = w >> 1, wc = w & 1;
  const int row0 = blockIdx.y * 128;
  const int col0 = blockIdx.x * 128;

  // staging: each wave covers 32 rows of each tile; 4 instrs x (8 rows x 64 cols)
  const int srow = w * 32 + (lane >> 3);
  const int scg = (lane & 7) * 8;
  const unsigned short* ap = A + (size_t)(row0 + srow) * K + scg;
  const unsigned short* bp = Bt + (size_t)(col0 + srow) * K + scg;

  const f32x4 fz = {0.f, 0.f, 0.f, 0.f};
  f32x4 acc[4][4];
#pragma unroll
  for (int i = 0; i < 4; ++i)
#pragma unroll
    for (int j = 0; j < 4; ++j) acc[i][j] = fz;

  for (int k0 = 0; k0 < K; k0 += 64) {
#pragma unroll
    for (int i = 0; i < 4; ++i) {
      __builtin_amdgcn_global_load_lds(
          (const __attribute__((address_space(1))) unsigned int*)(ap + (size_t)i * 8 * K + k0),
          (__attribute__((address_space(3))) unsigned int*)&lsA[(w * 32 + i * 8) * 64],
          16, 0, 0);
      __builtin_amdgcn_global_load_lds(
          (const __attribute__((address_space(1))) unsigned int*)(bp + (size_t)i * 8 * K + k0),
          (__attribute__((address_space(3))) unsigned int*)&lsB[(w * 32 + i * 8) * 64],
          16, 0, 0);
    }
    __syncthreads();
#pragma unroll
    for (int kk = 0; kk < 2; ++kk) {
      bf16x8 af[4], bfr[4];
#pragma unroll
      for (int mt = 0; mt < 4; ++mt)
        af[mt] = *(const bf16x8*)&lsA[(wr * 64 + mt * 16 + l16) * 64 + kk * 32 + quad * 8];
#pragma unroll
      for (int nt = 0; nt < 4; ++nt)
        bfr[nt] = *(const bf16x8*)&lsB[(wc * 64 + nt * 16 + l16) * 64 + kk * 32 + quad * 8];
#pragma unroll
      for (int mt = 0; mt < 4; ++mt)
#pragma unroll
        for (int nt = 0; nt < 4; ++nt)
          acc[mt][nt] = __builtin_amdgcn_mfma_f32_16x16x32_bf16(af[mt], bfr[nt], acc[mt][nt], 0, 0, 0);
    }
    __syncthreads();
  }

  const int rb = row0 + wr * 64;
  const int cb = col0 + wc * 64;
#pragma unroll
  for (int mt = 0; mt < 4; ++mt) {
#pragma unroll
    for (int nt = 0; nt < 4; ++nt) {
      const int r = rb + mt * 16 + quad * 4;
      const int c = cb + nt * 16 + l16;
#pragma unroll
      for (int i = 0; i < 4; ++i) {
        const float v = acc[mt][nt][i];
        const size_t idx = (size_t)(r + i) * N + c;
        if (mode == 0) ((float*)out)[idx] = v;
        else if (mode == 1) ((unsigned short*)out)[idx] = f2b(v);
        else if (mode == 2) ((float*)out)[idx] = v + res[idx];
        else ((unsigned short*)out)[(size_t)c * M + (r + i)] = f2b(v);
      }
    }
  }
}

// ---------------------------------------------------------------------------
// LayerNorm over D=1024, one token per 256-thread block, bf16 out.
// ---------------------------------------------------------------------------
__global__ __launch_bounds__(256) void ln_kernel(
    const float* __restrict__ x, const float* __restrict__ g,
    const float* __restrict__ be, unsigned short* __restrict__ out) {
  __shared__ float sbuf[4];
  const int t = blockIdx.x, tid = threadIdx.x;
  const float* row = x + (size_t)t * 1024;
  float v[4], s = 0.f;
#pragma unroll
  for (int j = 0; j < 4; ++j) { v[j] = row[tid + j * 256]; s += v[j]; }
#pragma unroll
  for (int off = 32; off; off >>= 1) s += __shfl_xor(s, off);
  if ((tid & 63) == 0) sbuf[tid >> 6] = s;
  __syncthreads();
  const float mu = (sbuf[0] + sbuf[1] + sbuf[2] + sbuf[3]) * (1.f / 1024.f);
  __syncthreads();
  float ss = 0.f;
#pragma unroll
  for (int j = 0; j < 4; ++j) { const float d = v[j] - mu; ss += d * d; }
#pragma unroll
  for (int off = 32; off; off >>= 1) ss += __shfl_xor(ss, off);
  if ((tid & 63) == 0) sbuf[tid >> 6] = ss;
  __syncthreads();
  const float var = (sbuf[0] + sbuf[1] + sbuf[2] + sbuf[3]) * (1.f / 1024.f);
  const float rstd = rsqrtf(var + 1e-5f);
  unsigned short* orow = out + (size_t)t * 1024;
#pragma unroll
  for (int j = 0; j < 4; ++j) {
    const int c = tid + j * 256;
    orow[c] = f2b((v[j] - mu) * rstd * g[c] + be[c]);
  }
}

// ---------------------------------------------------------------------------
// Attention mixing: h_{q,k,v}[r] = sum_n w_f*[n]*all_h[t, (base)+n*64+r];
// t_*[t, n*64+r] = w_r*[n]*h_*[r].  all_h cols: [0,2048)=f_qk, [2048,4096)=f_v.
// ---------------------------------------------------------------------------
__global__ __launch_bounds__(256) void mix_attn(
    const unsigned short* __restrict__ all_h,
    const float* __restrict__ w_fq, const float* __restrict__ w_fk,
    const float* __restrict__ w_fv, const float* __restrict__ w_rq,
    const float* __restrict__ w_rk, const float* __restrict__ w_rv,
    unsigned short* __restrict__ t_qk, unsigned short* __restrict__ t_v) {
  __shared__ float hq[64], hk[64], hv[64];
  const int t = blockIdx.x, tid = threadIdx.x;
  const int wv = tid >> 6, lane = tid & 63;
  const unsigned short* row = all_h + (size_t)t * 4096;
  if (wv < 3) {
    const float* wf = (wv == 0 ? w_fq : wv == 1 ? w_fk : w_fv) + (size_t)t * 32;
    const int base = (wv == 2) ? 2048 : 0;
    float acc = 0.f;
#pragma unroll
    for (int n = 0; n < 32; ++n) acc += wf[n] * b2f(row[base + n * 64 + lane]);
    (wv == 0 ? hq : wv == 1 ? hk : hv)[lane] = acc;
  }
  __syncthreads();
  const float* wrq = w_rq + (size_t)t * 32;
  const float* wrk = w_rk + (size_t)t * 32;
  const float* wrv = w_rv + (size_t)t * 32;
  for (int idx = tid; idx < 2048; idx += 256) {
    const int n = idx >> 6, r = idx & 63;
    t_qk[(size_t)t * 2048 + idx] = f2b(wrq[n] * hq[r]);
    t_qk[(size_t)(4096 + t) * 2048 + idx] = f2b(wrk[n] * hk[r]);
    t_v[(size_t)t * 2048 + idx] = f2b(wrv[n] * hv[r]);
  }
}

// Knowledge mixing (RK=128): h[r]=sum_n w_f[n]*all_h[t,n*128+r]; t_know=w_r[n]*h[r]
__global__ __launch_bounds__(256) void mix_know(
    const unsigned short* __restrict__ all_h, const float* __restrict__ w_f,
    const float* __restrict__ w_r, unsigned short* __restrict__ t_know) {
  __shared__ float h[128];
  const int t = blockIdx.x, tid = threadIdx.x;
  const unsigned short* row = all_h + (size_t)t * 4096;
  if (tid < 128) {
    const float* wf = w_f + (size_t)t * 32;
    float acc = 0.f;
#pragma unroll
    for (int n = 0; n < 32; ++n) acc += wf[n] * b2f(row[n * 128 + tid]);
    h[tid] = acc;
  }
  __syncthreads();
  const float* wr = w_r + (size_t)t * 32;
  for (int idx = tid; idx < 4096; idx += 256) {
    const int n = idx >> 7, r = idx & 127;
    t_know[(size_t)t * 4096 + idx] = f2b(wr[n] * h[r]);
  }
}

// ---------------------------------------------------------------------------
// Batched transpose + fp32->bf16: in [batch][R][C] f32 -> out [batch][C][R] bf16
// ---------------------------------------------------------------------------
__global__ __launch_bounds__(256) void transpose_bf(
    const float* __restrict__ in, unsigned short* __restrict__ out, int R, int C) {
  __shared__ float tile[32][33];
  const int bb = blockIdx.z;
  const int c0 = blockIdx.x * 32, r0 = blockIdx.y * 32;
  const int tx = threadIdx.x, ty = threadIdx.y;
  const float* ip = in + (size_t)bb * R * C;
  unsigned short* op = out + (size_t)bb * R * C;
#pragma unroll
  for (int j = 0; j < 4; ++j)
    tile[ty + j * 8][tx] = ip[(size_t)(r0 + ty + j * 8) * C + c0 + tx];
  __syncthreads();
#pragma unroll
  for (int j = 0; j < 4; ++j)
    op[(size_t)(c0 + ty + j * 8) * R + r0 + tx] = f2b(tile[tx][ty + j * 8]);
}

__global__ __launch_bounds__(256) void convert_bf(
    const float* __restrict__ in, unsigned short* __restrict__ out, int n) {
  const int i = blockIdx.x * 256 + threadIdx.x;
  if (i < n) out[i] = f2b(in[i]);
}

// ---------------------------------------------------------------------------
// Causal flash attention v3: LDS-staged double-buffered K/V with
//  (a) ds_reads issued BEFORE next-tile prefetch (no alias-drain stall),
//  (b) XOR chunk swizzle -> conflict-free fragment reads,
//  (c) exp2-folded softmax scale, (d) long blocks dispatched first.
// Q,K: bf16 [4096,1024] token-major; VT: bf16 [1024,4096] d-major.
// LDS slot (row, c') holds global 16B-chunk c' ^ (row&7).
// ---------------------------------------------------------------------------
__global__ __launch_bounds__(256) void flash_attn(
    const unsigned short* __restrict__ Q, const unsigned short* __restrict__ Kp,
    const unsigned short* __restrict__ VT, unsigned short* __restrict__ O) {
  __shared__ unsigned short Kls[2][64 * 64];
  __shared__ unsigned short Vls[2][64 * 64];
  __shared__ unsigned short Pl[4][16][64];
  const int qt = (gridDim.x - 1) - blockIdx.x;  // longest blocks first
  const int bh = blockIdx.y;
  const int b = bh >> 4, h = bh & 15;
  const int tid = threadIdx.x;
  const int w = tid >> 6, lane = tid & 63, quad = lane >> 4, l16 = lane & 15;
  const int tb = b * 2048;
  const int qrow = qt * 64 + w * 16;
  const float C = 0.18033688f;  // (1/sqrt(64)) * log2(e)

  // staging source offsets: lane loads swizzled chunk (lane&7)^(lane>>3)
  const int srow = (lane >> 3);                      // row within 8-row group
  const int scol = ((lane & 7) ^ srow) * 8;          // swizzled elem offset

  bf16x8 qf[2];
#pragma unroll
  for (int kk = 0; kk < 2; ++kk)
    qf[kk] = *(const bf16x8*)&Q[(size_t)(tb + qrow + l16) * 1024 + h * 64 + kk * 32 + quad * 8];

  const f32x4 fz = {0.f, 0.f, 0.f, 0.f};
  float m_i[4] = {-1e30f, -1e30f, -1e30f, -1e30f};
  float l_i[4] = {0.f, 0.f, 0.f, 0.f};
  f32x4 o_acc[4];
#pragma unroll
  for (int nt = 0; nt < 4; ++nt) o_acc[nt] = fz;

  auto stage = [&](int buf, int kt) {
#pragma unroll
    for (int j = 0; j < 2; ++j) {
      const int rg = (w * 2 + j) * 8 + srow;  // 0..63
      __builtin_amdgcn_global_load_lds(
          (const __attribute__((address_space(1))) unsigned int*)
              (Kp + (size_t)(tb + kt * 64 + rg) * 1024 + h * 64 + scol),
          (__attribute__((address_space(3))) unsigned int*)&Kls[buf][(w * 2 + j) * 8 * 64],
          16, 0, 0);
      __builtin_amdgcn_global_load_lds(
          (const __attribute__((address_space(1))) unsigned int*)
              (VT + (size_t)(h * 64 + rg) * 4096 + tb + kt * 64 + scol),
          (__attribute__((address_space(3))) unsigned int*)&Vls[buf][(w * 2 + j) * 8 * 64],
          16, 0, 0);
    }
  };

  stage(0, 0);
  __syncthreads();
  int buf = 0;
  for (int kt = 0; kt <= qt; ++kt) {
    // (a) all fragment reads FIRST, then prefetch -> no vmcnt drain on reads
    bf16x8 kf[8], vf[8];
#pragma unroll
    for (int kk = 0; kk < 2; ++kk)
#pragma unroll
      for (int nt = 0; nt < 4; ++nt) {
        const int sl = (((kk * 4 + quad) ^ (l16 & 7)) * 8);  // (b) swizzled
        kf[kk * 4 + nt] = *(const bf16x8*)&Kls[buf][(nt * 16 + l16) * 64 + sl];
        vf[kk * 4 + nt] = *(const bf16x8*)&Vls[buf][(nt * 16 + l16) * 64 + sl];
      }
    if (kt < qt) stage(buf ^ 1, kt + 1);

    f32x4 s[4];
#pragma unroll
    for (int nt = 0; nt < 4; ++nt) s[nt] = fz;
#pragma unroll
    for (int kk = 0; kk < 2; ++kk)
#pragma unroll
      for (int nt = 0; nt < 4; ++nt)
        s[nt] = __builtin_amdgcn_mfma_f32_16x16x32_bf16(qf[kk], kf[kk * 4 + nt], s[nt], 0, 0, 0);

    const bool diag = (kt == qt);
    float mx[4] = {-1e30f, -1e30f, -1e30f, -1e30f};
#pragma unroll
    for (int nt = 0; nt < 4; ++nt)
#pragma unroll
      for (int i = 0; i < 4; ++i) {
        float v = s[nt][i];  // raw score; scale folded into exp2
        if (diag && (nt * 16 + l16) > (w * 16 + quad * 4 + i)) v = -1e30f;
        s[nt][i] = v;
        mx[i] = fmaxf(mx[i], v);
      }
#pragma unroll
    for (int off = 1; off < 16; off <<= 1)
#pragma unroll
      for (int i = 0; i < 4; ++i) mx[i] = fmaxf(mx[i], __shfl_xor(mx[i], off));
    float al[4], rs[4], mC[4];
#pragma unroll
    for (int i = 0; i < 4; ++i) {
      const float mn = fmaxf(m_i[i], mx[i]);
      al[i] = exp2f((m_i[i] - mn) * C);
      m_i[i] = mn;
      mC[i] = mn * C;
      rs[i] = 0.f;
    }
#pragma unroll
    for (int nt = 0; nt < 4; ++nt)
#pragma unroll
      for (int i = 0; i < 4; ++i) {
        const float p = exp2f(fmaf(s[nt][i], C, -mC[i]));
        s[nt][i] = p;
        rs[i] += p;
      }
#pragma unroll
    for (int off = 1; off < 16; off <<= 1)
#pragma unroll
      for (int i = 0; i < 4; ++i) rs[i] += __shfl_xor(rs[i], off);
#pragma unroll
    for (int i = 0; i < 4; ++i) l_i[i] = l_i[i] * al[i] + rs[i];
#pragma unroll
    for (int nt = 0; nt < 4; ++nt)
#pragma unroll
      for (int i = 0; i < 4; ++i) o_acc[nt][i] *= al[i];
    // P (C-layout) -> A-frag via per-wave LDS round-trip (no cross-wave sync)
#pragma unroll
    for (int nt = 0; nt < 4; ++nt)
#pragma unroll
      for (int i = 0; i < 4; ++i) Pl[w][quad * 4 + i][nt * 16 + l16] = f2b(s[nt][i]);
    bf16x8 pf[2];
#pragma unroll
    for (int kk = 0; kk < 2; ++kk)
      pf[kk] = *(const bf16x8*)&Pl[w][l16][kk * 32 + quad * 8];
#pragma unroll
    for (int kk = 0; kk < 2; ++kk)
#pragma unroll
      for (int nt = 0; nt < 4; ++nt)
        o_acc[nt] = __builtin_amdgcn_mfma_f32_16x16x32_bf16(pf[kk], vf[kk * 4 + nt], o_acc[nt], 0, 0, 0);
    __syncthreads();  // drains prefetch vmcnt + guards LDS buffer swap
    buf ^= 1;
  }
#pragma unroll
  for (int nt = 0; nt < 4; ++nt)
#pragma unroll
    for (int i = 0; i < 4; ++i)
      O[(size_t)(tb + qrow + quad * 4 + i) * 1024 + h * 64 + nt * 16 + l16] =
          f2b(o_acc[nt][i] / l_i[i]);
}

// ---------------------------------------------------------------------------
extern "C" void kernel_launch(void* const* d_in, const int* in_sizes, int n_in,
                              void* d_out, int out_size, void* d_ws, size_t ws_size,
                              hipStream_t stream) {
  (void)in_sizes; (void)n_in; (void)out_size; (void)ws_size;
  const float* x      = (const float*)d_in[0];
  const float* f_qk   = (const float*)d_in[1];
  const float* f_v    = (const float*)d_in[2];
  const float* r_qk   = (const float*)d_in[3];
  const float* r_v    = (const float*)d_in[4];
  const float* f_know = (const float*)d_in[5];
  const float* r_know = (const float*)d_in[6];
  const float* W_O    = (const float*)d_in[7];
  const float* gamma1 = (const float*)d_in[8];
  const float* beta1  = (const float*)d_in[9];
  const float* gamma2 = (const float*)d_in[10];
  const float* beta2  = (const float*)d_in[11];
  const float* w_fq   = (const float*)d_in[12];
  const float* w_fk   = (const float*)d_in[13];
  const float* w_fv   = (const float*)d_in[14];
  const float* w_rq   = (const float*)d_in[15];
  const float* w_rk   = (const float*)d_in[16];
  const float* w_rv   = (const float*)d_in[17];
  const float* w_kf   = (const float*)d_in[18];
  const float* w_kr   = (const float*)d_in[19];

  char* base = (char*)d_ws;
  size_t off = 0;
  auto alloc = [&](size_t b) { char* p = base + off; off += (b + 255) & ~(size_t)255; return p; };
  // persistent bf16 weight layouts ([N][K] for gemm_bt)
  unsigned short* fcomb   = (unsigned short*)alloc(8388608);   // [4096][1024]: rows 0..2047 f_qk, 2048.. f_v
  unsigned short* fknowT  = (unsigned short*)alloc(8388608);   // [4096][1024]
  unsigned short* r_qkT   = (unsigned short*)alloc(4194304);   // [1024][2048]
  unsigned short* r_vT    = (unsigned short*)alloc(4194304);   // [1024][2048]
  unsigned short* r_knowT = (unsigned short*)alloc(8388608);   // [1024][4096]
  unsigned short* WO_bf   = (unsigned short*)alloc(2097152);   // [1024][1024] (natural = [N][K])
  // activations
  unsigned short* nx_bf   = (unsigned short*)alloc(8388608);   // [4096][1024] (reused for LN2)
  unsigned short* all_h   = (unsigned short*)alloc(33554432);  // [4096][4096] bf16 (reused, knowledge)
  unsigned short* t_qk    = (unsigned short*)alloc(33554432);  // [8192][2048] (reused as t_know [4096][4096])
  unsigned short* t_v     = (unsigned short*)alloc(16777216);  // [4096][2048]; later reused as x1 fp32
  unsigned short* QKbuf   = (unsigned short*)alloc(16777216);  // [8192][1024] bf16: Q rows 0..4095, K rows 4096..
  unsigned short* VT      = (unsigned short*)alloc(8388608);   // [1024][4096] bf16
  unsigned short* attn    = (unsigned short*)alloc(8388608);   // [4096][1024] bf16
  float* x1 = (float*)t_v;  // t_v dead before x1 written

  const dim3 blk256(256), blkT(32, 8);

  // weight preps
  transpose_bf<<<dim3(2, 32, 32), blkT, 0, stream>>>(f_qk, fcomb, 1024, 64);
  transpose_bf<<<dim3(2, 32, 32), blkT, 0, stream>>>(f_v, fcomb + (size_t)2048 * 1024, 1024, 64);
  transpose_bf<<<dim3(4, 32, 32), blkT, 0, stream>>>(f_know, fknowT, 1024, 128);
  transpose_bf<<<dim3(32, 64, 1), blkT, 0, stream>>>(r_qk, r_qkT, 2048, 1024);
  transpose_bf<<<dim3(32, 64, 1), blkT, 0, stream>>>(r_v, r_vT, 2048, 1024);
  transpose_bf<<<dim3(32, 128, 1), blkT, 0, stream>>>(r_know, r_knowT, 4096, 1024);
  convert_bf<<<4096, blk256, 0, stream>>>(W_O, WO_bf, 1048576);

  // attention circuit
  ln_kernel<<<4096, blk256, 0, stream>>>(x, gamma1, beta1, nx_bf);
  gemm_bt<<<dim3(32, 32), blk256, 0, stream>>>(nx_bf, fcomb, nullptr, all_h, 4096, 4096, 1024, 1);
  mix_attn<<<4096, blk256, 0, stream>>>(all_h, w_fq, w_fk, w_fv, w_rq, w_rk, w_rv, t_qk, t_v);
  gemm_bt<<<dim3(8, 64), blk256, 0, stream>>>(t_qk, r_qkT, nullptr, QKbuf, 8192, 1024, 2048, 1);
  gemm_bt<<<dim3(8, 32), blk256, 0, stream>>>(t_v, r_vT, nullptr, VT, 4096, 1024, 2048, 3);
  flash_attn<<<dim3(32, 32), blk256, 0, stream>>>(QKbuf, QKbuf + (size_t)4096 * 1024, VT, attn);
  gemm_bt<<<dim3(8, 32), blk256, 0, stream>>>(attn, WO_bf, x, x1, 4096, 1024, 1024, 2);

  // knowledge circuit
  ln_kernel<<<4096, blk256, 0, stream>>>(x1, gamma2, beta2, nx_bf);
  gemm_bt<<<dim3(32, 32), blk256, 0, stream>>>(nx_bf, fknowT, nullptr, all_h, 4096, 4096, 1024, 1);
  mix_know<<<4096, blk256, 0, stream>>>(all_h, w_kf, w_kr, t_qk);
  gemm_bt<<<dim3(8, 32), blk256, 0, stream>>>(t_qk, r_knowT, x1, (float*)d_out, 4096, 1024, 4096, 2);
}

// Round 4
// 674.625 us; speedup vs baseline: 1.1836x; 1.0464x over previous
//
#include <hip/hip_runtime.h>
#include <stdint.h>

// B=2,S=2048,D=1024,H=16,R=64,N=32,RK=128,DH=64. Tokens T=4096.
// Pipeline (all bf16 MFMA, fp32 accumulate, fp32 residuals):
//  transposes -> LN1 -> G_feat1 -> mix_attn -> G_qk/G_v -> flash -> G_O(+x)
//  -> LN2 -> G_feat2 -> mix_know -> G_know(+x1) -> d_out

typedef __bf16 bf16x8 __attribute__((ext_vector_type(8)));
typedef float f32x4 __attribute__((ext_vector_type(4)));

__device__ __forceinline__ unsigned short f2b(float f) {
  union { float f; unsigned u; } v; v.f = f;
  unsigned u = v.u;
  unsigned r = (u + 0x7FFFu + ((u >> 16) & 1u)) >> 16;  // RNE
  return (unsigned short)r;
}
__device__ __forceinline__ float b2f(unsigned short h) {
  union { unsigned u; float f; } v; v.u = ((unsigned)h) << 16;
  return v.f;
}
__device__ __forceinline__ unsigned pk2(float lo, float hi) {
  return (unsigned)f2b(lo) | ((unsigned)f2b(hi) << 16);
}

// ---------------------------------------------------------------------------
// Generic bf16 GEMM: C[M,N] = A[M,K] @ Bt[N,K]^T.  128x128 tile, BK=64,
// 256 threads (4 waves, 2x2 of 64x64), 16x16x32 MFMA, global_load_lds x16.
// mode 0: fp32 out; 1: bf16 out; 2: fp32 out + res; 3: bf16 transposed out[N,M]
// ---------------------------------------------------------------------------
__global__ __launch_bounds__(256) void gemm_bt(
    const unsigned short* __restrict__ A, const unsigned short* __restrict__ Bt,
    const float* __restrict__ res, void* __restrict__ out,
    int M, int N, int K, int mode) {
  __shared__ unsigned short lsA[128 * 64];
  __shared__ unsigned short lsB[128 * 64];
  const int tid = threadIdx.x;
  const int w = tid >> 6, lane = tid & 63;
  const int quad = lane >> 4, l16 = lane & 15;
  const int wr = w >> 1, wc = w & 1;
  const int row0 = blockIdx.y * 128;
  const int col0 = blockIdx.x * 128;

  // staging: each wave covers 32 rows of each tile; 4 instrs x (8 rows x 64 cols)
  const int srow = w * 32 + (lane >> 3);
  const int scg = (lane & 7) * 8;
  const unsigned short* ap = A + (size_t)(row0 + srow) * K + scg;
  const unsigned short* bp = Bt + (size_t)(col0 + srow) * K + scg;

  const f32x4 fz = {0.f, 0.f, 0.f, 0.f};
  f32x4 acc[4][4];
#pragma unroll
  for (int i = 0; i < 4; ++i)
#pragma unroll
    for (int j = 0; j < 4; ++j) acc[i][j] = fz;

  for (int k0 = 0; k0 < K; k0 += 64) {
#pragma unroll
    for (int i = 0; i < 4; ++i) {
      __builtin_amdgcn_global_load_lds(
          (const __attribute__((address_space(1))) unsigned int*)(ap + (size_t)i * 8 * K + k0),
          (__attribute__((address_space(3))) unsigned int*)&lsA[(w * 32 + i * 8) * 64],
          16, 0, 0);
      __builtin_amdgcn_global_load_lds(
          (const __attribute__((address_space(1))) unsigned int*)(bp + (size_t)i * 8 * K + k0),
          (__attribute__((address_space(3))) unsigned int*)&lsB[(w * 32 + i * 8) * 64],
          16, 0, 0);
    }
    __syncthreads();
#pragma unroll
    for (int kk = 0; kk < 2; ++kk) {
      bf16x8 af[4], bfr[4];
#pragma unroll
      for (int mt = 0; mt < 4; ++mt)
        af[mt] = *(const bf16x8*)&lsA[(wr * 64 + mt * 16 + l16) * 64 + kk * 32 + quad * 8];
#pragma unroll
      for (int nt = 0; nt < 4; ++nt)
        bfr[nt] = *(const bf16x8*)&lsB[(wc * 64 + nt * 16 + l16) * 64 + kk * 32 + quad * 8];
#pragma unroll
      for (int mt = 0; mt < 4; ++mt)
#pragma unroll
        for (int nt = 0; nt < 4; ++nt)
          acc[mt][nt] = __builtin_amdgcn_mfma_f32_16x16x32_bf16(af[mt], bfr[nt], acc[mt][nt], 0, 0, 0);
    }
    __syncthreads();
  }

  const int rb = row0 + wr * 64;
  const int cb = col0 + wc * 64;
#pragma unroll
  for (int mt = 0; mt < 4; ++mt) {
#pragma unroll
    for (int nt = 0; nt < 4; ++nt) {
      const int r = rb + mt * 16 + quad * 4;
      const int c = cb + nt * 16 + l16;
#pragma unroll
      for (int i = 0; i < 4; ++i) {
        const float v = acc[mt][nt][i];
        const size_t idx = (size_t)(r + i) * N + c;
        if (mode == 0) ((float*)out)[idx] = v;
        else if (mode == 1) ((unsigned short*)out)[idx] = f2b(v);
        else if (mode == 2) ((float*)out)[idx] = v + res[idx];
        else ((unsigned short*)out)[(size_t)c * M + (r + i)] = f2b(v);
      }
    }
  }
}

// ---------------------------------------------------------------------------
// LayerNorm over D=1024, one token per 256-thread block, bf16 out.
// ---------------------------------------------------------------------------
__global__ __launch_bounds__(256) void ln_kernel(
    const float* __restrict__ x, const float* __restrict__ g,
    const float* __restrict__ be, unsigned short* __restrict__ out) {
  __shared__ float sbuf[4];
  const int t = blockIdx.x, tid = threadIdx.x;
  const float* row = x + (size_t)t * 1024;
  float v[4], s = 0.f;
#pragma unroll
  for (int j = 0; j < 4; ++j) { v[j] = row[tid + j * 256]; s += v[j]; }
#pragma unroll
  for (int off = 32; off; off >>= 1) s += __shfl_xor(s, off);
  if ((tid & 63) == 0) sbuf[tid >> 6] = s;
  __syncthreads();
  const float mu = (sbuf[0] + sbuf[1] + sbuf[2] + sbuf[3]) * (1.f / 1024.f);
  __syncthreads();
  float ss = 0.f;
#pragma unroll
  for (int j = 0; j < 4; ++j) { const float d = v[j] - mu; ss += d * d; }
#pragma unroll
  for (int off = 32; off; off >>= 1) ss += __shfl_xor(ss, off);
  if ((tid & 63) == 0) sbuf[tid >> 6] = ss;
  __syncthreads();
  const float var = (sbuf[0] + sbuf[1] + sbuf[2] + sbuf[3]) * (1.f / 1024.f);
  const float rstd = rsqrtf(var + 1e-5f);
  unsigned short* orow = out + (size_t)t * 1024;
#pragma unroll
  for (int j = 0; j < 4; ++j) {
    const int c = tid + j * 256;
    orow[c] = f2b((v[j] - mu) * rstd * g[c] + be[c]);
  }
}

// ---------------------------------------------------------------------------
// Attention mixing: h_{q,k,v}[r] = sum_n w_f*[n]*all_h[t, (base)+n*64+r];
// t_*[t, n*64+r] = w_r*[n]*h_*[r].  all_h cols: [0,2048)=f_qk, [2048,4096)=f_v.
// ---------------------------------------------------------------------------
__global__ __launch_bounds__(256) void mix_attn(
    const unsigned short* __restrict__ all_h,
    const float* __restrict__ w_fq, const float* __restrict__ w_fk,
    const float* __restrict__ w_fv, const float* __restrict__ w_rq,
    const float* __restrict__ w_rk, const float* __restrict__ w_rv,
    unsigned short* __restrict__ t_qk, unsigned short* __restrict__ t_v) {
  __shared__ float hq[64], hk[64], hv[64];
  const int t = blockIdx.x, tid = threadIdx.x;
  const int wv = tid >> 6, lane = tid & 63;
  const unsigned short* row = all_h + (size_t)t * 4096;
  if (wv < 3) {
    const float* wf = (wv == 0 ? w_fq : wv == 1 ? w_fk : w_fv) + (size_t)t * 32;
    const int base = (wv == 2) ? 2048 : 0;
    float acc = 0.f;
#pragma unroll
    for (int n = 0; n < 32; ++n) acc += wf[n] * b2f(row[base + n * 64 + lane]);
    (wv == 0 ? hq : wv == 1 ? hk : hv)[lane] = acc;
  }
  __syncthreads();
  const float* wrq = w_rq + (size_t)t * 32;
  const float* wrk = w_rk + (size_t)t * 32;
  const float* wrv = w_rv + (size_t)t * 32;
  for (int idx = tid; idx < 2048; idx += 256) {
    const int n = idx >> 6, r = idx & 63;
    t_qk[(size_t)t * 2048 + idx] = f2b(wrq[n] * hq[r]);
    t_qk[(size_t)(4096 + t) * 2048 + idx] = f2b(wrk[n] * hk[r]);
    t_v[(size_t)t * 2048 + idx] = f2b(wrv[n] * hv[r]);
  }
}

// Knowledge mixing (RK=128): h[r]=sum_n w_f[n]*all_h[t,n*128+r]; t_know=w_r[n]*h[r]
__global__ __launch_bounds__(256) void mix_know(
    const unsigned short* __restrict__ all_h, const float* __restrict__ w_f,
    const float* __restrict__ w_r, unsigned short* __restrict__ t_know) {
  __shared__ float h[128];
  const int t = blockIdx.x, tid = threadIdx.x;
  const unsigned short* row = all_h + (size_t)t * 4096;
  if (tid < 128) {
    const float* wf = w_f + (size_t)t * 32;
    float acc = 0.f;
#pragma unroll
    for (int n = 0; n < 32; ++n) acc += wf[n] * b2f(row[n * 128 + tid]);
    h[tid] = acc;
  }
  __syncthreads();
  const float* wr = w_r + (size_t)t * 32;
  for (int idx = tid; idx < 4096; idx += 256) {
    const int n = idx >> 7, r = idx & 127;
    t_know[(size_t)t * 4096 + idx] = f2b(wr[n] * h[r]);
  }
}

// ---------------------------------------------------------------------------
// Batched transpose + fp32->bf16: in [batch][R][C] f32 -> out [batch][C][R] bf16
// ---------------------------------------------------------------------------
__global__ __launch_bounds__(256) void transpose_bf(
    const float* __restrict__ in, unsigned short* __restrict__ out, int R, int C) {
  __shared__ float tile[32][33];
  const int bb = blockIdx.z;
  const int c0 = blockIdx.x * 32, r0 = blockIdx.y * 32;
  const int tx = threadIdx.x, ty = threadIdx.y;
  const float* ip = in + (size_t)bb * R * C;
  unsigned short* op = out + (size_t)bb * R * C;
#pragma unroll
  for (int j = 0; j < 4; ++j)
    tile[ty + j * 8][tx] = ip[(size_t)(r0 + ty + j * 8) * C + c0 + tx];
  __syncthreads();
#pragma unroll
  for (int j = 0; j < 4; ++j)
    op[(size_t)(c0 + ty + j * 8) * R + r0 + tx] = f2b(tile[tx][ty + j * 8]);
}

__global__ __launch_bounds__(256) void convert_bf(
    const float* __restrict__ in, unsigned short* __restrict__ out, int n) {
  const int i = blockIdx.x * 256 + threadIdx.x;
  if (i < n) out[i] = f2b(in[i]);
}

// ---------------------------------------------------------------------------
// Causal flash attention v4: transposed algebra.
//   S^T = K·Q^T  (C/D col=l16 -> q-row; each lane owns ONE q, 16 k in regs)
//   softmax: per-lane reduce over 16 regs + 2 shuffles (xor16/32); m,l,alpha scalar/lane
//   O^T = V^T·P^T; P^T C-layout -> B-frag via quad-pair ds_bpermute exchange
// LDS: double-buffered K/V only (32 KB). No P round-trip, no bank conflicts.
// Q,K: bf16 [4096,1024] token-major; VT: bf16 [1024,4096] d-major.
// LDS slot (row, c') holds global 16B-chunk c' ^ (row&7)  (XOR swizzle).
// ---------------------------------------------------------------------------
__global__ __launch_bounds__(256) void flash_attn(
    const unsigned short* __restrict__ Q, const unsigned short* __restrict__ Kp,
    const unsigned short* __restrict__ VT, unsigned short* __restrict__ O) {
  __shared__ unsigned short Kls[2][64 * 64];
  __shared__ unsigned short Vls[2][64 * 64];
  const int qt = (gridDim.x - 1) - blockIdx.x;  // longest blocks first
  const int bh = blockIdx.y;
  const int b = bh >> 4, h = bh & 15;
  const int tid = threadIdx.x;
  const int w = tid >> 6, lane = tid & 63, quad = lane >> 4, l16 = lane & 15;
  const int tb = b * 2048;
  const int qrow = qt * 64 + w * 16;
  const float C = 0.18033688f;  // (1/sqrt(64)) * log2(e)

  // staging source offsets: lane loads swizzled chunk (lane&7)^(lane>>3)
  const int srow = (lane >> 3);                      // row within 8-row group
  const int scol = ((lane & 7) ^ srow) * 8;          // swizzled elem offset

  // Q fragment (B-operand): n = q-row = l16, k = kk*32 + quad*8 + j
  bf16x8 qf[2];
#pragma unroll
  for (int kk = 0; kk < 2; ++kk)
    qf[kk] = *(const bf16x8*)&Q[(size_t)(tb + qrow + l16) * 1024 + h * 64 + kk * 32 + quad * 8];

  const f32x4 fz = {0.f, 0.f, 0.f, 0.f};
  float m_i = -1e30f, l_i = 0.f;          // per-lane (q = l16) scalars
  f32x4 o_acc[4];                          // O^T: d = nt*16+quad*4+i, q = l16
#pragma unroll
  for (int nt = 0; nt < 4; ++nt) o_acc[nt] = fz;

  auto stage = [&](int buf, int kt) {
#pragma unroll
    for (int j = 0; j < 2; ++j) {
      const int rg = (w * 2 + j) * 8 + srow;  // 0..63
      __builtin_amdgcn_global_load_lds(
          (const __attribute__((address_space(1))) unsigned int*)
              (Kp + (size_t)(tb + kt * 64 + rg) * 1024 + h * 64 + scol),
          (__attribute__((address_space(3))) unsigned int*)&Kls[buf][(w * 2 + j) * 8 * 64],
          16, 0, 0);
      __builtin_amdgcn_global_load_lds(
          (const __attribute__((address_space(1))) unsigned int*)
              (VT + (size_t)(h * 64 + rg) * 4096 + tb + kt * 64 + scol),
          (__attribute__((address_space(3))) unsigned int*)&Vls[buf][(w * 2 + j) * 8 * 64],
          16, 0, 0);
    }
  };

  // bpermute source byte-addrs for the P^T quad-pair exchange (constant)
  const int srcA = (((quad & 1) * 32 + l16) << 2);
  const int srcB = srcA + 64;  // +16 lanes
  const bool hiq = (quad >= 2);

  stage(0, 0);
  __syncthreads();
  int buf = 0;
  for (int kt = 0; kt <= qt; ++kt) {
    // fragment reads first (no vmcnt dependence), then prefetch next tile
    bf16x8 kf[8], vf[8];
#pragma unroll
    for (int kk = 0; kk < 2; ++kk)
#pragma unroll
      for (int nt = 0; nt < 4; ++nt) {
        const int sl = (((kk * 4 + quad) ^ (l16 & 7)) * 8);  // swizzled chunk
        kf[kk * 4 + nt] = *(const bf16x8*)&Kls[buf][(nt * 16 + l16) * 64 + sl];
        vf[kk * 4 + nt] = *(const bf16x8*)&Vls[buf][(nt * 16 + l16) * 64 + sl];
      }
    if (kt < qt) stage(buf ^ 1, kt + 1);

    const bool diag = (kt == qt);
    // S^T = K·Q^T : A = K-frag (m = k-token), B = Q-frag (n = q-row)
    f32x4 s[4];
#pragma unroll
    for (int nt = 0; nt < 4; ++nt) s[nt] = fz;
#pragma unroll
    for (int kk = 0; kk < 2; ++kk)
#pragma unroll
      for (int nt = 0; nt < 4; ++nt)
        if (!diag || nt <= w)  // wave-uniform skip of fully-masked diag tiles
          s[nt] = __builtin_amdgcn_mfma_f32_16x16x32_bf16(kf[kk * 4 + nt], qf[kk], s[nt], 0, 0, 0);

    // mask + per-lane max over 16 regs
    const int qloc = w * 16 + l16;
    float mx = -1e30f;
#pragma unroll
    for (int nt = 0; nt < 4; ++nt)
#pragma unroll
      for (int i = 0; i < 4; ++i) {
        float v = s[nt][i];
        if (diag && (nt * 16 + quad * 4 + i) > qloc) v = -1e30f;
        s[nt][i] = v;
        mx = fmaxf(mx, v);
      }
    mx = fmaxf(mx, __shfl_xor(mx, 16));
    mx = fmaxf(mx, __shfl_xor(mx, 32));
    const float mn = fmaxf(m_i, mx);
    const float al = exp2f((m_i - mn) * C);
    m_i = mn;
    const float mC = mn * C;
    float rs = 0.f;
#pragma unroll
    for (int nt = 0; nt < 4; ++nt)
#pragma unroll
      for (int i = 0; i < 4; ++i) {
        const float p = exp2f(fmaf(s[nt][i], C, -mC));
        s[nt][i] = p;
        rs += p;
      }
    rs += __shfl_xor(rs, 16);
    rs += __shfl_xor(rs, 32);
    l_i = l_i * al + rs;
#pragma unroll
    for (int nt = 0; nt < 4; ++nt)
#pragma unroll
      for (int i = 0; i < 4; ++i) o_acc[nt][i] *= al;

    // P^T (C-layout) -> B-frag via quad-pair exchange.
    // pk[nt][r] packs (i=2r, i=2r+1) as bf16x2.
    unsigned pk[4][2];
#pragma unroll
    for (int nt = 0; nt < 4; ++nt) {
      pk[nt][0] = pk2(s[nt][0], s[nt][1]);
      pk[nt][1] = pk2(s[nt][2], s[nt][3]);
    }
#pragma unroll
    for (int kk = 0; kk < 2; ++kk) {
      const int ea = 2 * kk, eb = 2 * kk + 1;
      const unsigned u0 = __builtin_amdgcn_ds_bpermute(srcA, pk[ea][0]);
      const unsigned u1 = __builtin_amdgcn_ds_bpermute(srcA, pk[ea][1]);
      const unsigned u2 = __builtin_amdgcn_ds_bpermute(srcB, pk[ea][0]);
      const unsigned u3 = __builtin_amdgcn_ds_bpermute(srcB, pk[ea][1]);
      const unsigned w0 = __builtin_amdgcn_ds_bpermute(srcA, pk[eb][0]);
      const unsigned w1 = __builtin_amdgcn_ds_bpermute(srcA, pk[eb][1]);
      const unsigned w2 = __builtin_amdgcn_ds_bpermute(srcB, pk[eb][0]);
      const unsigned w3 = __builtin_amdgcn_ds_bpermute(srcB, pk[eb][1]);
      unsigned dw[4];
      dw[0] = hiq ? w0 : u0;
      dw[1] = hiq ? w1 : u1;
      dw[2] = hiq ? w2 : u2;
      dw[3] = hiq ? w3 : u3;
      const bf16x8 pf = *(const bf16x8*)dw;
      // O^T = V^T·P^T : A = V^T-frag (m = d), B = P^T-frag (n = q)
#pragma unroll
      for (int nt = 0; nt < 4; ++nt)
        o_acc[nt] = __builtin_amdgcn_mfma_f32_16x16x32_bf16(vf[kk * 4 + nt], pf, o_acc[nt], 0, 0, 0);
    }
    __syncthreads();  // drains prefetch vmcnt + guards LDS buffer swap
    buf ^= 1;
  }
  // epilogue: O^T regs -> O[token][d]; lane q = l16, d = nt*16 + quad*4 + i
  const float inv = 1.0f / l_i;
  unsigned short* orow = O + (size_t)(tb + qrow + l16) * 1024 + h * 64;
#pragma unroll
  for (int nt = 0; nt < 4; ++nt) {
    const unsigned d0 = pk2(o_acc[nt][0] * inv, o_acc[nt][1] * inv);
    const unsigned d1 = pk2(o_acc[nt][2] * inv, o_acc[nt][3] * inv);
    *(unsigned*)&orow[nt * 16 + quad * 4] = d0;
    *(unsigned*)&orow[nt * 16 + quad * 4 + 2] = d1;
  }
}

// ---------------------------------------------------------------------------
extern "C" void kernel_launch(void* const* d_in, const int* in_sizes, int n_in,
                              void* d_out, int out_size, void* d_ws, size_t ws_size,
                              hipStream_t stream) {
  (void)in_sizes; (void)n_in; (void)out_size; (void)ws_size;
  const float* x      = (const float*)d_in[0];
  const float* f_qk   = (const float*)d_in[1];
  const float* f_v    = (const float*)d_in[2];
  const float* r_qk   = (const float*)d_in[3];
  const float* r_v    = (const float*)d_in[4];
  const float* f_know = (const float*)d_in[5];
  const float* r_know = (const float*)d_in[6];
  const float* W_O    = (const float*)d_in[7];
  const float* gamma1 = (const float*)d_in[8];
  const float* beta1  = (const float*)d_in[9];
  const float* gamma2 = (const float*)d_in[10];
  const float* beta2  = (const float*)d_in[11];
  const float* w_fq   = (const float*)d_in[12];
  const float* w_fk   = (const float*)d_in[13];
  const float* w_fv   = (const float*)d_in[14];
  const float* w_rq   = (const float*)d_in[15];
  const float* w_rk   = (const float*)d_in[16];
  const float* w_rv   = (const float*)d_in[17];
  const float* w_kf   = (const float*)d_in[18];
  const float* w_kr   = (const float*)d_in[19];

  char* base = (char*)d_ws;
  size_t off = 0;
  auto alloc = [&](size_t b) { char* p = base + off; off += (b + 255) & ~(size_t)255; return p; };
  // persistent bf16 weight layouts ([N][K] for gemm_bt)
  unsigned short* fcomb   = (unsigned short*)alloc(8388608);   // [4096][1024]: rows 0..2047 f_qk, 2048.. f_v
  unsigned short* fknowT  = (unsigned short*)alloc(8388608);   // [4096][1024]
  unsigned short* r_qkT   = (unsigned short*)alloc(4194304);   // [1024][2048]
  unsigned short* r_vT    = (unsigned short*)alloc(4194304);   // [1024][2048]
  unsigned short* r_knowT = (unsigned short*)alloc(8388608);   // [1024][4096]
  unsigned short* WO_bf   = (unsigned short*)alloc(2097152);   // [1024][1024] (natural = [N][K])
  // activations
  unsigned short* nx_bf   = (unsigned short*)alloc(8388608);   // [4096][1024] (reused for LN2)
  unsigned short* all_h   = (unsigned short*)alloc(33554432);  // [4096][4096] bf16 (reused, knowledge)
  unsigned short* t_qk    = (unsigned short*)alloc(33554432);  // [8192][2048] (reused as t_know [4096][4096])
  unsigned short* t_v     = (unsigned short*)alloc(16777216);  // [4096][2048]; later reused as x1 fp32
  unsigned short* QKbuf   = (unsigned short*)alloc(16777216);  // [8192][1024] bf16: Q rows 0..4095, K rows 4096..
  unsigned short* VT      = (unsigned short*)alloc(8388608);   // [1024][4096] bf16
  unsigned short* attn    = (unsigned short*)alloc(8388608);   // [4096][1024] bf16
  float* x1 = (float*)t_v;  // t_v dead before x1 written

  const dim3 blk256(256), blkT(32, 8);

  // weight preps
  transpose_bf<<<dim3(2, 32, 32), blkT, 0, stream>>>(f_qk, fcomb, 1024, 64);
  transpose_bf<<<dim3(2, 32, 32), blkT, 0, stream>>>(f_v, fcomb + (size_t)2048 * 1024, 1024, 64);
  transpose_bf<<<dim3(4, 32, 32), blkT, 0, stream>>>(f_know, fknowT, 1024, 128);
  transpose_bf<<<dim3(32, 64, 1), blkT, 0, stream>>>(r_qk, r_qkT, 2048, 1024);
  transpose_bf<<<dim3(32, 64, 1), blkT, 0, stream>>>(r_v, r_vT, 2048, 1024);
  transpose_bf<<<dim3(32, 128, 1), blkT, 0, stream>>>(r_know, r_knowT, 4096, 1024);
  convert_bf<<<4096, blk256, 0, stream>>>(W_O, WO_bf, 1048576);

  // attention circuit
  ln_kernel<<<4096, blk256, 0, stream>>>(x, gamma1, beta1, nx_bf);
  gemm_bt<<<dim3(32, 32), blk256, 0, stream>>>(nx_bf, fcomb, nullptr, all_h, 4096, 4096, 1024, 1);
  mix_attn<<<4096, blk256, 0, stream>>>(all_h, w_fq, w_fk, w_fv, w_rq, w_rk, w_rv, t_qk, t_v);
  gemm_bt<<<dim3(8, 64), blk256, 0, stream>>>(t_qk, r_qkT, nullptr, QKbuf, 8192, 1024, 2048, 1);
  gemm_bt<<<dim3(8, 32), blk256, 0, stream>>>(t_v, r_vT, nullptr, VT, 4096, 1024, 2048, 3);
  flash_attn<<<dim3(32, 32), blk256, 0, stream>>>(QKbuf, QKbuf + (size_t)4096 * 1024, VT, attn);
  gemm_bt<<<dim3(8, 32), blk256, 0, stream>>>(attn, WO_bf, x, x1, 4096, 1024, 1024, 2);

  // knowledge circuit
  ln_kernel<<<4096, blk256, 0, stream>>>(x1, gamma2, beta2, nx_bf);
  gemm_bt<<<dim3(32, 32), blk256, 0, stream>>>(nx_bf, fknowT, nullptr, all_h, 4096, 4096, 1024, 1);
  mix_know<<<4096, blk256, 0, stream>>>(all_h, w_kf, w_kr, t_qk);
  gemm_bt<<<dim3(8, 32), blk256, 0, stream>>>(t_qk, r_knowT, x1, (float*)d_out, 4096, 1024, 4096, 2);
}